// Round 14
// baseline (3165.718 us; speedup 1.0000x reference)
//
#include <hip/hip_runtime.h>

#define HID    64
#define TSTEPS 256
#define BATCH  2048

typedef float v4f __attribute__((ext_vector_type(4)));

// tanh(x) = 1 - 2/(exp2(2*log2(e)*x) + 1); exact at saturation
__device__ __forceinline__ float fast_tanh(float x) {
    float e = __builtin_amdgcn_exp2f(x * 2.8853900817779268f);
    float r = __builtin_amdgcn_rcpf(e + 1.0f);
    return fmaf(-2.0f, r, 1.0f);
}

// ds_swizzle xor-exchange within 32-lane halves (BitMode: xor=M, and=0x1F)
template <int M>
__device__ __forceinline__ float swz(float v) {
    return __int_as_float(__builtin_amdgcn_ds_swizzle(
        __float_as_int(v), (M << 10) | 0x1F));
}

// DPP move. 0xB1 quad_perm=lane^1, 0x4E quad_perm=lane^2, 0x128 row_ror:8 (==lane^8)
template <int CTRL>
__device__ __forceinline__ float dppx(float x) {
    int xi = __float_as_int(x);
    return __int_as_float(__builtin_amdgcn_update_dpp(xi, xi, CTRL, 0xF, 0xF, false));
}

__device__ __forceinline__ float bperm(int addr, float v) {
    return __int_as_float(__builtin_amdgcn_ds_bpermute(addr, __float_as_int(v)));
}

// full 64-lane sum via DPP rotates + row broadcasts; uniform result (lane 63)
__device__ __forceinline__ float wave_sum(float v) {
    v += dppx<0x121>(v);                       // ror:1
    v += dppx<0x122>(v);                       // ror:2
    v += dppx<0x124>(v);                       // ror:4
    v += dppx<0x128>(v);                       // ror:8  -> 16-row totals
    v += __int_as_float(__builtin_amdgcn_update_dpp(
            0, __float_as_int(v), 0x142, 0xA, 0xF, false));   // bcast15
    v += __int_as_float(__builtin_amdgcn_update_dpp(
            0, __float_as_int(v), 0x143, 0xC, 0xF, false));   // bcast31
    return __int_as_float(__builtin_amdgcn_readlane(__float_as_int(v), 63));
}

__device__ __forceinline__ constexpr int rev3(int x) {   // 3-bit reversal
    return ((x & 1) << 2) | (x & 2) | ((x >> 2) & 1);
}

__global__ __launch_bounds__(256) __attribute__((amdgpu_waves_per_eu(2, 2)))
void hnn_rk4_kernel(
        const float* __restrict__ tarr,
        const float* __restrict__ x0,
        const float* __restrict__ W1,
        const float* __restrict__ b1,
        const float* __restrict__ W2,
        const float* __restrict__ b2,
        const float* __restrict__ W3,
        float* __restrict__ out)
{
    const int lane = threadIdx.x & 63;
    const int wid  = threadIdx.x >> 6;
    const int b    = blockIdx.x * 4 + wid;     // one wave per batch element

    // per-wave 64-float broadcast buffer, indexed by UNIT number
    __shared__ alignas(16) float sbuf[4][64];
    float* sb = sbuf[wid];

    // 8x8 lane grid (proven R8/R12): lane (rr,cc) owns W2 rows 8rr..+7 x cols
    // 8cc..+7, hidden unit uo = 8rr+rev3(cc); ends holding u[vu], vu = 8cc+rev3(rr).
    const int rr = lane >> 3, cc = lane & 7;
    const int pc = rev3(cc),  pr = rev3(rr);
    const int uo = 8 * rr + pc;
    const int vu = 8 * cc + pr;

    const float dt  = tarr[1] - tarr[0];
    const float hdt = 0.5f * dt;
    const float sdt = dt * (1.0f / 6.0f);

    const float w1a = W1[2 * uo + 0];
    const float w1b = W1[2 * uo + 1];
    const float b1i = b1[uo];
    const float b2i = b2[uo];
    const float w3i = W3[uo];
    const float w1vb  = W1[2 * vu + 1];
    const float nw1va = -W1[2 * vu + 0];       // folded negate for kp

    int a32 = (lane ^ 32) * 4;                 // xor32 exchange (backward tail)

    // Weight scalars, slot-permuted (R8/R12 layout):
    //   wF[t][k] = W2[8rr + (k^pc)][8cc + t]   (forward: slot k, input t)
    //   wB[o][k] = W2[8rr + o][8cc + (k^pr)]   (backward: slot k, input o)
    float wF[8][8], wB[8][8];
#pragma unroll
    for (int t = 0; t < 8; ++t) {
#pragma unroll
        for (int k = 0; k < 8; ++k) {
            wF[t][k] = W2[(8 * rr + (k ^ pc)) * HID + 8 * cc + t];
            wB[t][k] = W2[(8 * rr + t) * HID + 8 * cc + (k ^ pr)];
        }
    }
    // Commit all weights to AGPRs: AGPR-pinned values cannot be spilled to
    // scratch or remat-reloaded from global; plain-C fma uses let the compiler
    // source them directly (AV operand classes) if gfx950 VALU supports it.
#pragma unroll
    for (int t = 0; t < 8; ++t)
#pragma unroll
        for (int k = 0; k < 8; ++k)
            asm("" : "+a"(wF[t][k]), "+a"(wB[t][k]));

    float q = x0[2 * b + 0];
    float p = x0[2 * b + 1];

    if (lane == 0) {
        out[2 * b + 0] = q;
        out[2 * b + 1] = p;
    }

    auto dynamics = [&](float xq, float xp, float& kq, float& kp) {
        // layer 1 (own unit)
        const float h1 = fast_tanh(fmaf(w1a, xq, fmaf(w1b, xp, b1i)));

        // ---- broadcast h1 via LDS: scatter-write by unit, contiguous b128 reads
        // (same-wave DS in-order; no barrier — R2/R12 proven)
        sb[uo] = h1;
        const v4f r0 = *(const v4f*)(sb + 8 * cc);      // h1[8cc+0..3]
        const v4f r1 = *(const v4f*)(sb + 8 * cc + 4);  // h1[8cc+4..7]
        const float h1v = sb[vu];                       // h1 of held unit vu
        const float h[8] = {r0.x, r0.y, r0.z, r0.w, r1.x, r1.y, r1.z, r1.w};

        // ---- forward: pre2 = W2 h1 + b2 (slot k accumulates over t) ----
        float A0 = 0.f, A1 = 0.f, A2 = 0.f, A3 = 0.f;
        float A4 = 0.f, A5 = 0.f, A6 = 0.f, A7 = 0.f;
#pragma unroll
        for (int t = 0; t < 8; ++t) {
            A0 = fmaf(h[t], wF[t][0], A0);
            A1 = fmaf(h[t], wF[t][1], A1);
            A2 = fmaf(h[t], wF[t][2], A2);
            A3 = fmaf(h[t], wF[t][3], A3);
            A4 = fmaf(h[t], wF[t][4], A4);
            A5 = fmaf(h[t], wF[t][5], A5);
            A6 = fmaf(h[t], wF[t][6], A6);
            A7 = fmaf(h[t], wF[t][7], A7);
        }
        // uniform scatter-reduce over cc bits (same tree/order as R12)
        A0 += dppx<0xB1>(A4);  A1 += dppx<0xB1>(A5);
        A2 += dppx<0xB1>(A6);  A3 += dppx<0xB1>(A7);
        A0 += dppx<0x4E>(A2);  A1 += dppx<0x4E>(A3);
        const float pre2 = A0 + swz<4>(A1) + b2i;

        const float h2 = fast_tanh(pre2);
        const float g2 = w3i * fmaf(-h2, h2, 1.0f);

        // ---- broadcast g2 via LDS (h1 reads already retired: in-order pipe)
        sb[uo] = g2;
        const v4f s0 = *(const v4f*)(sb + 8 * rr);      // g2[8rr+0..3]
        const v4f s1 = *(const v4f*)(sb + 8 * rr + 4);  // g2[8rr+4..7]
        const float g[8] = {s0.x, s0.y, s0.z, s0.w, s1.x, s1.y, s1.z, s1.w};

        // ---- backward: u = W2^T g2 (slot k accumulates over o) ----
        float B0 = 0.f, B1 = 0.f, B2 = 0.f, B3 = 0.f;
        float B4 = 0.f, B5 = 0.f, B6 = 0.f, B7 = 0.f;
#pragma unroll
        for (int o = 0; o < 8; ++o) {
            B0 = fmaf(g[o], wB[o][0], B0);
            B1 = fmaf(g[o], wB[o][1], B1);
            B2 = fmaf(g[o], wB[o][2], B2);
            B3 = fmaf(g[o], wB[o][3], B3);
            B4 = fmaf(g[o], wB[o][4], B4);
            B5 = fmaf(g[o], wB[o][5], B5);
            B6 = fmaf(g[o], wB[o][6], B6);
            B7 = fmaf(g[o], wB[o][7], B7);
        }
        // scatter-reduce over rr bits (same tree/order as R12)
        B0 += dppx<0x128>(B4);  B1 += dppx<0x128>(B5);
        B2 += dppx<0x128>(B6);  B3 += dppx<0x128>(B7);
        B0 += swz<16>(B2);      B1 += swz<16>(B3);
        const float uv = B0 + bperm(a32, B1);          // = u[vu], stays here

        // dH/dx contribution of unit vu; wave_sum is landing-agnostic
        const float g1v = uv * fmaf(-h1v, h1v, 1.0f);

        kq = wave_sum(g1v * w1vb);    //  dH/dp
        kp = wave_sum(g1v * nw1va);   // -dH/dq (negate pre-folded)
    };

#pragma unroll 1
    for (int s = 0; s < TSTEPS - 1; ++s) {
        // re-pin each step: keeps the weight live ranges AGPR-class through
        // the loop body (no copy-out to arch VGPRs, no spill)
#pragma unroll
        for (int t = 0; t < 8; ++t)
#pragma unroll
            for (int k = 0; k < 8; ++k)
                asm("" : "+a"(wF[t][k]), "+a"(wB[t][k]));

        float kq1, kp1, kq2, kp2, kq3, kp3, kq4, kp4;
        dynamics(q, p, kq1, kp1);
        dynamics(fmaf(hdt, kq1, q), fmaf(hdt, kp1, p), kq2, kp2);
        dynamics(fmaf(hdt, kq2, q), fmaf(hdt, kp2, p), kq3, kp3);
        dynamics(fmaf(dt,  kq3, q), fmaf(dt,  kp3, p), kq4, kp4);
        q = fmaf(sdt, (kq1 + kq4) + 2.0f * (kq2 + kq3), q);
        p = fmaf(sdt, (kp1 + kp4) + 2.0f * (kp2 + kp3), p);
        if (lane == 0) {
            out[(s + 1) * (BATCH * 2) + 2 * b + 0] = q;
            out[(s + 1) * (BATCH * 2) + 2 * b + 1] = p;
        }
    }
}

extern "C" void kernel_launch(void* const* d_in, const int* in_sizes, int n_in,
                              void* d_out, int out_size, void* d_ws, size_t ws_size,
                              hipStream_t stream) {
    const float* t  = (const float*)d_in[0];
    const float* x0 = (const float*)d_in[1];
    const float* W1 = (const float*)d_in[2];
    const float* b1 = (const float*)d_in[3];
    const float* W2 = (const float*)d_in[4];
    const float* b2 = (const float*)d_in[5];
    const float* W3 = (const float*)d_in[6];
    // d_in[7] = b3: additive constant in H, cancels in dH/dx — unused.

    hnn_rk4_kernel<<<dim3(BATCH / 4), dim3(256), 0, stream>>>(
        t, x0, W1, b1, W2, b2, W3, (float*)d_out);
}

// Round 15
// 1558.378 us; speedup vs baseline: 2.0314x; 2.0314x over previous
//
#include <hip/hip_runtime.h>

#define HID    64
#define TSTEPS 256
#define BATCH  2048

#if defined(__has_builtin)
#  if __has_builtin(__builtin_amdgcn_permlane16_swap)
#    define HAVE_PL16 1
#  endif
#  if __has_builtin(__builtin_amdgcn_permlane32_swap)
#    define HAVE_PL32 1
#  endif
#endif

typedef unsigned int u32x2 __attribute__((ext_vector_type(2)));

// tanh(x) = 1 - 2/(exp2(2*log2(e)*x) + 1); exact at saturation
__device__ __forceinline__ float fast_tanh(float x) {
    float e = __builtin_amdgcn_exp2f(x * 2.8853900817779268f);
    float r = __builtin_amdgcn_rcpf(e + 1.0f);
    return fmaf(-2.0f, r, 1.0f);
}

// ds_swizzle xor-exchange (fallback path only)
template <int M>
__device__ __forceinline__ float swz(float v) {
    return __int_as_float(__builtin_amdgcn_ds_swizzle(
        __float_as_int(v), (M << 10) | 0x1F));
}

// DPP move: 0xB1 quad_perm lane^1, 0x4E quad_perm lane^2,
// 0x121/0x124/0x128/0x12C row_ror:1/4/8/12 (within 16-lane rows)
template <int CTRL>
__device__ __forceinline__ float dppx(float x) {
    int xi = __float_as_int(x);
    return __int_as_float(__builtin_amdgcn_update_dpp(xi, xi, CTRL, 0xF, 0xF, false));
}

__device__ __forceinline__ float bperm(int addr, float v) {
    return __int_as_float(__builtin_amdgcn_ds_bpermute(addr, __float_as_int(v)));
}

// y[lane] = v[lane^4]: ror:4 is right for (lane&4)==0, ror:12 for (lane&4)!=0
__device__ __forceinline__ float xor4v(float v, bool m4) {
    float a = dppx<0x124>(v);
    float c = dppx<0x12C>(v);
    return m4 ? c : a;
}

// y[lane] = v[lane^16] via permlane16_swap builtin (VALU); DS fallback
__device__ __forceinline__ float xchg16(float v, bool m16) {
#ifdef HAVE_PL16
    u32x2 r = __builtin_amdgcn_permlane16_swap(
        __float_as_uint(v), __float_as_uint(v), false, false);
    return m16 ? __uint_as_float(r.x) : __uint_as_float(r.y);
#else
    (void)m16;
    return swz<16>(v);
#endif
}

// y[lane] = v[lane^32] via permlane32_swap builtin (VALU); DS fallback
__device__ __forceinline__ float xchg32(float v, bool m32, int a32) {
#ifdef HAVE_PL32
    (void)a32;
    u32x2 r = __builtin_amdgcn_permlane32_swap(
        __float_as_uint(v), __float_as_uint(v), false, false);
    return m32 ? __uint_as_float(r.x) : __uint_as_float(r.y);
#else
    (void)m32;
    return bperm(a32, v);
#endif
}

// full 64-lane sum via DPP rotates + row broadcasts; uniform result (lane 63)
__device__ __forceinline__ float wave_sum(float v) {
    v += dppx<0x121>(v);                       // ror:1
    v += dppx<0x122>(v);                       // ror:2
    v += dppx<0x124>(v);                       // ror:4
    v += dppx<0x128>(v);                       // ror:8  -> 16-row totals
    v += __int_as_float(__builtin_amdgcn_update_dpp(
            0, __float_as_int(v), 0x142, 0xA, 0xF, false));   // bcast15
    v += __int_as_float(__builtin_amdgcn_update_dpp(
            0, __float_as_int(v), 0x143, 0xC, 0xF, false));   // bcast31
    return __int_as_float(__builtin_amdgcn_readlane(__float_as_int(v), 63));
}

__device__ __forceinline__ constexpr int rev3(int x) {   // 3-bit reversal
    return ((x & 1) << 2) | (x & 2) | ((x >> 2) & 1);
}

__global__ __launch_bounds__(256) __attribute__((amdgpu_waves_per_eu(2, 2)))
void hnn_rk4_kernel(
        const float* __restrict__ tarr,
        const float* __restrict__ x0,
        const float* __restrict__ W1,
        const float* __restrict__ b1,
        const float* __restrict__ W2,
        const float* __restrict__ b2,
        const float* __restrict__ W3,
        float* __restrict__ out)
{
    const int lane = threadIdx.x & 63;
    const int wid  = threadIdx.x >> 6;
    const int b    = blockIdx.x * 4 + wid;     // one wave per batch element

    // 8x8 lane grid: lane (rr,cc) owns W2 rows 8rr..+7 x cols 8cc..+7.
    // (q,p) are wave-uniform -> h1 of the col-group is recomputed LOCALLY
    // (no cross-lane); pre2 is ALL-reduced over cc-lanes so h2/g2 of the
    // row-group is local too. Zero DS ops in the whole eval.
    const int rr = lane >> 3, cc = lane & 7;
    const int pr = rev3(rr);
    const int vu = 8 * cc + pr;                // unit whose u this lane ends up with

    const float dt  = tarr[1] - tarr[0];
    const float hdt = 0.5f * dt;
    const float sdt = dt * (1.0f / 6.0f);

    // layer-1 params of the col-group units 8cc+t (for local h1 recompute)
    float w1ca[8], w1cb[8], b1c[8];
#pragma unroll
    for (int t = 0; t < 8; ++t) {
        w1ca[t] = W1[2 * (8 * cc + t) + 0];
        w1cb[t] = W1[2 * (8 * cc + t) + 1];
        b1c[t]  = b1[8 * cc + t];
    }
    // layer-1 params of unit vu (for g1v) + wave_sum weights
    const float w1vA = W1[2 * vu + 0];
    const float w1vB = W1[2 * vu + 1];
    const float b1v  = b1[vu];
    const float nw1vA = -w1vA;

    // layer-2 output params of the row-group units 8rr+k
    float b2r[8], w3r[8];
#pragma unroll
    for (int k = 0; k < 8; ++k) {
        b2r[k] = b2[8 * rr + k];
        w3r[k] = W3[8 * rr + k];
    }

    // weights: forward wF[t][k] = W2[8rr+k][8cc+t] (plain layout);
    // backward wB[o][k] = W2[8rr+o][8cc+(k^pr)] (pr-permuted for the uniform
    // scatter-reduce: lane^8 <-> slot^4, lane^16 <-> slot^2, lane^32 <-> slot^1)
    float wF[8][8], wB[8][8];
#pragma unroll
    for (int t = 0; t < 8; ++t) {
#pragma unroll
        for (int k = 0; k < 8; ++k) {
            wF[t][k] = W2[(8 * rr + k) * HID + 8 * cc + t];
            wB[t][k] = W2[(8 * rr + t) * HID + 8 * cc + (k ^ pr)];
        }
    }

    const bool m4 = lane & 4, m16 = lane & 16, m32 = lane & 32;
    const int a32 = (lane ^ 32) * 4;           // fallback addr for xchg32

    float q = x0[2 * b + 0];
    float p = x0[2 * b + 1];

    if (lane == 0) {
        out[2 * b + 0] = q;
        out[2 * b + 1] = p;
    }

    auto dynamics = [&](float xq, float xp, float& kq, float& kp) {
        // ---- local h1 for the col-group (8 independent tanh chains) ----
        float h[8];
#pragma unroll
        for (int t = 0; t < 8; ++t)
            h[t] = fast_tanh(fmaf(w1ca[t], xq, fmaf(w1cb[t], xp, b1c[t])));
        const float h1v = fast_tanh(fmaf(w1vA, xq, fmaf(w1vB, xp, b1v)));

        // ---- forward partials: A[k] = sum_t h[t] * W2[8rr+k][8cc+t] ----
        float A0 = 0.f, A1 = 0.f, A2 = 0.f, A3 = 0.f;
        float A4 = 0.f, A5 = 0.f, A6 = 0.f, A7 = 0.f;
#pragma unroll
        for (int t = 0; t < 8; ++t) {
            A0 = fmaf(h[t], wF[t][0], A0);
            A1 = fmaf(h[t], wF[t][1], A1);
            A2 = fmaf(h[t], wF[t][2], A2);
            A3 = fmaf(h[t], wF[t][3], A3);
            A4 = fmaf(h[t], wF[t][4], A4);
            A5 = fmaf(h[t], wF[t][5], A5);
            A6 = fmaf(h[t], wF[t][6], A6);
            A7 = fmaf(h[t], wF[t][7], A7);
        }
        // ---- ALL-reduce over cc-lanes (bits 0,1,2): every lane of the
        // row-group gets the full pre2 of all 8 row-group units. Pure VALU.
        A0 += dppx<0xB1>(A0);  A1 += dppx<0xB1>(A1);
        A2 += dppx<0xB1>(A2);  A3 += dppx<0xB1>(A3);
        A4 += dppx<0xB1>(A4);  A5 += dppx<0xB1>(A5);
        A6 += dppx<0xB1>(A6);  A7 += dppx<0xB1>(A7);
        A0 += dppx<0x4E>(A0);  A1 += dppx<0x4E>(A1);
        A2 += dppx<0x4E>(A2);  A3 += dppx<0x4E>(A3);
        A4 += dppx<0x4E>(A4);  A5 += dppx<0x4E>(A5);
        A6 += dppx<0x4E>(A6);  A7 += dppx<0x4E>(A7);
        A0 += xor4v(A0, m4);   A1 += xor4v(A1, m4);
        A2 += xor4v(A2, m4);   A3 += xor4v(A3, m4);
        A4 += xor4v(A4, m4);   A5 += xor4v(A5, m4);
        A6 += xor4v(A6, m4);   A7 += xor4v(A7, m4);

        // ---- local h2/g2 for the row-group units ----
        float g2l[8];
        {
            float pre[8] = {A0 + b2r[0], A1 + b2r[1], A2 + b2r[2], A3 + b2r[3],
                            A4 + b2r[4], A5 + b2r[5], A6 + b2r[6], A7 + b2r[7]};
#pragma unroll
            for (int k = 0; k < 8; ++k) {
                const float h2 = fast_tanh(pre[k]);
                g2l[k] = w3r[k] * fmaf(-h2, h2, 1.0f);
            }
        }

        // ---- backward partials: B[k] = sum_o g2l[o] * W2[8rr+o][8cc+(k^pr)] ----
        float B0 = 0.f, B1 = 0.f, B2 = 0.f, B3 = 0.f;
        float B4 = 0.f, B5 = 0.f, B6 = 0.f, B7 = 0.f;
#pragma unroll
        for (int o = 0; o < 8; ++o) {
            B0 = fmaf(g2l[o], wB[o][0], B0);
            B1 = fmaf(g2l[o], wB[o][1], B1);
            B2 = fmaf(g2l[o], wB[o][2], B2);
            B3 = fmaf(g2l[o], wB[o][3], B3);
            B4 = fmaf(g2l[o], wB[o][4], B4);
            B5 = fmaf(g2l[o], wB[o][5], B5);
            B6 = fmaf(g2l[o], wB[o][6], B6);
            B7 = fmaf(g2l[o], wB[o][7], B7);
        }
        // scatter-reduce over rr bits: lane^8 (DPP), lane^16 / lane^32 (permlane)
        B0 += dppx<0x128>(B4);  B1 += dppx<0x128>(B5);
        B2 += dppx<0x128>(B6);  B3 += dppx<0x128>(B7);
        B0 += xchg16(B2, m16);  B1 += xchg16(B3, m16);
        const float uv = B0 + xchg32(B1, m32, a32);   // = u[vu], stays here

        // dH/dx contribution of unit vu; wave_sum is landing-agnostic
        const float g1v = uv * fmaf(-h1v, h1v, 1.0f);

        kq = wave_sum(g1v * w1vB);    //  dH/dp
        kp = wave_sum(g1v * nw1vA);   // -dH/dq (negate pre-folded)
    };

#pragma unroll 1
    for (int s = 0; s < TSTEPS - 1; ++s) {
        float kq1, kp1, kq2, kp2, kq3, kp3, kq4, kp4;
        dynamics(q, p, kq1, kp1);
        dynamics(fmaf(hdt, kq1, q), fmaf(hdt, kp1, p), kq2, kp2);
        dynamics(fmaf(hdt, kq2, q), fmaf(hdt, kp2, p), kq3, kp3);
        dynamics(fmaf(dt,  kq3, q), fmaf(dt,  kp3, p), kq4, kp4);
        q = fmaf(sdt, (kq1 + kq4) + 2.0f * (kq2 + kq3), q);
        p = fmaf(sdt, (kp1 + kp4) + 2.0f * (kp2 + kp3), p);
        if (lane == 0) {
            out[(s + 1) * (BATCH * 2) + 2 * b + 0] = q;
            out[(s + 1) * (BATCH * 2) + 2 * b + 1] = p;
        }
    }
}

extern "C" void kernel_launch(void* const* d_in, const int* in_sizes, int n_in,
                              void* d_out, int out_size, void* d_ws, size_t ws_size,
                              hipStream_t stream) {
    const float* t  = (const float*)d_in[0];
    const float* x0 = (const float*)d_in[1];
    const float* W1 = (const float*)d_in[2];
    const float* b1 = (const float*)d_in[3];
    const float* W2 = (const float*)d_in[4];
    const float* b2 = (const float*)d_in[5];
    const float* W3 = (const float*)d_in[6];
    // d_in[7] = b3: additive constant in H, cancels in dH/dx — unused.

    hnn_rk4_kernel<<<dim3(BATCH / 4), dim3(256), 0, stream>>>(
        t, x0, W1, b1, W2, b2, W3, (float*)d_out);
}

// Round 16
// 815.736 us; speedup vs baseline: 3.8808x; 1.9104x over previous
//
#include <hip/hip_runtime.h>

#define HID    64
#define TSTEPS 256
#define BATCH  2048

typedef float v4f __attribute__((ext_vector_type(4)));
typedef unsigned int u32x2 __attribute__((ext_vector_type(2)));

// tanh(x) = 1 - 2/(exp2(2*log2(e)*x) + 1); exact at saturation
__device__ __forceinline__ float fast_tanh(float x) {
    float e = __builtin_amdgcn_exp2f(x * 2.8853900817779268f);
    float r = __builtin_amdgcn_rcpf(e + 1.0f);
    return fmaf(-2.0f, r, 1.0f);
}

// DPP move: 0xB1 quad_perm lane^1, 0x4E quad_perm lane^2,
// 0x121/0x122/0x124/0x128/0x12C row_ror:1/2/4/8/12
template <int CTRL>
__device__ __forceinline__ float dppx(float x) {
    int xi = __float_as_int(x);
    return __int_as_float(__builtin_amdgcn_update_dpp(xi, xi, CTRL, 0xF, 0xF, false));
}

// y[lane] = v[lane^4] via row_ror (VALU) — R15 hardware-proven
__device__ __forceinline__ float xor4v(float v, bool m4) {
    float a = dppx<0x124>(v);
    float c = dppx<0x12C>(v);
    return m4 ? c : a;
}

// y[lane] = v[lane^16] via permlane16_swap builtin (VALU) — R15 hardware-proven
__device__ __forceinline__ float xchg16(float v, bool m16) {
    u32x2 r = __builtin_amdgcn_permlane16_swap(
        __float_as_uint(v), __float_as_uint(v), false, false);
    return m16 ? __uint_as_float(r.x) : __uint_as_float(r.y);
}

// y[lane] = v[lane^32] via permlane32_swap builtin (VALU) — R15 hardware-proven
__device__ __forceinline__ float xchg32(float v, bool m32) {
    u32x2 r = __builtin_amdgcn_permlane32_swap(
        __float_as_uint(v), __float_as_uint(v), false, false);
    return m32 ? __uint_as_float(r.x) : __uint_as_float(r.y);
}

// full 64-lane sum via DPP rotates + row broadcasts; uniform result (lane 63)
__device__ __forceinline__ float wave_sum(float v) {
    v += dppx<0x121>(v);                       // ror:1
    v += dppx<0x122>(v);                       // ror:2
    v += dppx<0x124>(v);                       // ror:4
    v += dppx<0x128>(v);                       // ror:8  -> 16-row totals
    v += __int_as_float(__builtin_amdgcn_update_dpp(
            0, __float_as_int(v), 0x142, 0xA, 0xF, false));   // bcast15
    v += __int_as_float(__builtin_amdgcn_update_dpp(
            0, __float_as_int(v), 0x143, 0xC, 0xF, false));   // bcast31
    return __int_as_float(__builtin_amdgcn_readlane(__float_as_int(v), 63));
}

__device__ __forceinline__ constexpr int rev3(int x) {   // 3-bit reversal
    return ((x & 1) << 2) | (x & 2) | ((x >> 2) & 1);
}

__global__ __launch_bounds__(256) __attribute__((amdgpu_waves_per_eu(2, 2)))
void hnn_rk4_kernel(
        const float* __restrict__ tarr,
        const float* __restrict__ x0,
        const float* __restrict__ W1,
        const float* __restrict__ b1,
        const float* __restrict__ W2,
        const float* __restrict__ b2,
        const float* __restrict__ W3,
        float* __restrict__ out)
{
    const int lane = threadIdx.x & 63;
    const int wid  = threadIdx.x >> 6;
    const int b    = blockIdx.x * 4 + wid;     // one wave per batch element

    // per-wave 64-float broadcast buffer, indexed by UNIT number
    __shared__ alignas(16) float sbuf[4][64];
    float* sb = sbuf[wid];

    // 8x8 lane grid (R8/R12 proven): lane (rr,cc) owns W2 rows 8rr..+7 x cols
    // 8cc..+7, hidden unit uo = 8rr+rev3(cc); ends holding u[vu], vu=8cc+rev3(rr).
    const int rr = lane >> 3, cc = lane & 7;
    const int pc = rev3(cc),  pr = rev3(rr);
    const int uo = 8 * rr + pc;
    const int vu = 8 * cc + pr;

    const float dt  = tarr[1] - tarr[0];
    const float hdt = 0.5f * dt;
    const float sdt = dt * (1.0f / 6.0f);

    const float w1a = W1[2 * uo + 0];
    const float w1b = W1[2 * uo + 1];
    const float b1i = b1[uo];
    const float b2i = b2[uo];
    const float w3i = W3[uo];
    const float w1vb  = W1[2 * vu + 1];
    const float nw1va = -W1[2 * vu + 0];       // folded negate for kp

    // Weight scalars, slot-permuted (R14 layout, proven absmax 0.0078125):
    //   wF[t][k] = W2[8rr + (k^pc)][8cc + t]   (forward: slot k, input t)
    //   wB[o][k] = W2[8rr + o][8cc + (k^pr)]   (backward: slot k, input o)
    float wF[8][8], wB[8][8];
#pragma unroll
    for (int t = 0; t < 8; ++t) {
#pragma unroll
        for (int k = 0; k < 8; ++k) {
            wF[t][k] = W2[(8 * rr + (k ^ pc)) * HID + 8 * cc + t];
            wB[t][k] = W2[(8 * rr + t) * HID + 8 * cc + (k ^ pr)];
        }
    }
    // setup-only pins (R12-proven safe; R14's in-loop "+a" re-pins caused
    // the 16 GB scratch disaster — never again)
#pragma unroll
    for (int t = 0; t < 8; ++t)
#pragma unroll
        for (int k = 0; k < 8; ++k)
            asm("" : "+v"(wF[t][k]), "+v"(wB[t][k]));

    const bool m4 = lane & 4, m16 = lane & 16, m32 = lane & 32;

    float q = x0[2 * b + 0];
    float p = x0[2 * b + 1];

    if (lane == 0) {
        out[2 * b + 0] = q;
        out[2 * b + 1] = p;
    }

    auto dynamics = [&](float xq, float xp, float& kq, float& kp) {
        // layer 1 (own unit)
        const float h1 = fast_tanh(fmaf(w1a, xq, fmaf(w1b, xp, b1i)));

        // ---- broadcast h1 via LDS: scatter-write by unit, contiguous b128
        // reads (same-wave DS in-order; no barrier — R2/R12 proven)
        sb[uo] = h1;
        const v4f r0 = *(const v4f*)(sb + 8 * cc);      // h1[8cc+0..3]
        const v4f r1 = *(const v4f*)(sb + 8 * cc + 4);  // h1[8cc+4..7]
        const float h1v = sb[vu];                       // h1 of held unit vu
        const float h[8] = {r0.x, r0.y, r0.z, r0.w, r1.x, r1.y, r1.z, r1.w};

        // ---- forward: pre2 = W2 h1 + b2 (slot k accumulates over t) ----
        float A0 = 0.f, A1 = 0.f, A2 = 0.f, A3 = 0.f;
        float A4 = 0.f, A5 = 0.f, A6 = 0.f, A7 = 0.f;
#pragma unroll
        for (int t = 0; t < 8; ++t) {
            A0 = fmaf(h[t], wF[t][0], A0);
            A1 = fmaf(h[t], wF[t][1], A1);
            A2 = fmaf(h[t], wF[t][2], A2);
            A3 = fmaf(h[t], wF[t][3], A3);
            A4 = fmaf(h[t], wF[t][4], A4);
            A5 = fmaf(h[t], wF[t][5], A5);
            A6 = fmaf(h[t], wF[t][6], A6);
            A7 = fmaf(h[t], wF[t][7], A7);
        }
        // uniform scatter-reduce over cc bits — all VALU (xor4 via row_ror)
        A0 += dppx<0xB1>(A4);  A1 += dppx<0xB1>(A5);
        A2 += dppx<0xB1>(A6);  A3 += dppx<0xB1>(A7);
        A0 += dppx<0x4E>(A2);  A1 += dppx<0x4E>(A3);
        const float pre2 = A0 + xor4v(A1, m4) + b2i;

        const float h2 = fast_tanh(pre2);
        const float g2 = w3i * fmaf(-h2, h2, 1.0f);

        // ---- broadcast g2 via LDS (h1 reads already retired: in-order pipe)
        sb[uo] = g2;
        const v4f s0 = *(const v4f*)(sb + 8 * rr);      // g2[8rr+0..3]
        const v4f s1 = *(const v4f*)(sb + 8 * rr + 4);  // g2[8rr+4..7]
        const float g[8] = {s0.x, s0.y, s0.z, s0.w, s1.x, s1.y, s1.z, s1.w};

        // ---- backward: u = W2^T g2 (slot k accumulates over o) ----
        float B0 = 0.f, B1 = 0.f, B2 = 0.f, B3 = 0.f;
        float B4 = 0.f, B5 = 0.f, B6 = 0.f, B7 = 0.f;
#pragma unroll
        for (int o = 0; o < 8; ++o) {
            B0 = fmaf(g[o], wB[o][0], B0);
            B1 = fmaf(g[o], wB[o][1], B1);
            B2 = fmaf(g[o], wB[o][2], B2);
            B3 = fmaf(g[o], wB[o][3], B3);
            B4 = fmaf(g[o], wB[o][4], B4);
            B5 = fmaf(g[o], wB[o][5], B5);
            B6 = fmaf(g[o], wB[o][6], B6);
            B7 = fmaf(g[o], wB[o][7], B7);
        }
        // scatter-reduce over rr bits — all VALU (xor8 DPP, xor16/32 permlane)
        B0 += dppx<0x128>(B4);  B1 += dppx<0x128>(B5);
        B2 += dppx<0x128>(B6);  B3 += dppx<0x128>(B7);
        B0 += xchg16(B2, m16);  B1 += xchg16(B3, m16);
        const float uv = B0 + xchg32(B1, m32);         // = u[vu], stays here

        // dH/dx contribution of unit vu; wave_sum is landing-agnostic
        const float g1v = uv * fmaf(-h1v, h1v, 1.0f);

        kq = wave_sum(g1v * w1vb);    //  dH/dp
        kp = wave_sum(g1v * nw1va);   // -dH/dq (negate pre-folded)
    };

#pragma unroll 1
    for (int s = 0; s < TSTEPS - 1; ++s) {
        float kq1, kp1, kq2, kp2, kq3, kp3, kq4, kp4;
        dynamics(q, p, kq1, kp1);
        dynamics(fmaf(hdt, kq1, q), fmaf(hdt, kp1, p), kq2, kp2);
        dynamics(fmaf(hdt, kq2, q), fmaf(hdt, kp2, p), kq3, kp3);
        dynamics(fmaf(dt,  kq3, q), fmaf(dt,  kp3, p), kq4, kp4);
        q = fmaf(sdt, (kq1 + kq4) + 2.0f * (kq2 + kq3), q);
        p = fmaf(sdt, (kp1 + kp4) + 2.0f * (kp2 + kp3), p);
        if (lane == 0) {
            out[(s + 1) * (BATCH * 2) + 2 * b + 0] = q;
            out[(s + 1) * (BATCH * 2) + 2 * b + 1] = p;
        }
    }
}

extern "C" void kernel_launch(void* const* d_in, const int* in_sizes, int n_in,
                              void* d_out, int out_size, void* d_ws, size_t ws_size,
                              hipStream_t stream) {
    const float* t  = (const float*)d_in[0];
    const float* x0 = (const float*)d_in[1];
    const float* W1 = (const float*)d_in[2];
    const float* b1 = (const float*)d_in[3];
    const float* W2 = (const float*)d_in[4];
    const float* b2 = (const float*)d_in[5];
    const float* W3 = (const float*)d_in[6];
    // d_in[7] = b3: additive constant in H, cancels in dH/dx — unused.

    hnn_rk4_kernel<<<dim3(BATCH / 4), dim3(256), 0, stream>>>(
        t, x0, W1, b1, W2, b2, W3, (float*)d_out);
}

// Round 17
// 729.606 us; speedup vs baseline: 4.3389x; 1.1181x over previous
//
#include <hip/hip_runtime.h>

#define HID    64
#define TSTEPS 256
#define BATCH  2048

typedef float v2f __attribute__((ext_vector_type(2)));
typedef float v4f __attribute__((ext_vector_type(4)));
typedef unsigned int u32x2 __attribute__((ext_vector_type(2)));

// tanh(x) = 1 - 2/(exp2(2*log2(e)*x) + 1); exact at saturation
__device__ __forceinline__ float fast_tanh(float x) {
    float e = __builtin_amdgcn_exp2f(x * 2.8853900817779268f);
    float r = __builtin_amdgcn_rcpf(e + 1.0f);
    return fmaf(-2.0f, r, 1.0f);
}

// DPP move: 0xB1 quad_perm lane^1, 0x4E quad_perm lane^2,
// 0x121/0x122/0x124/0x128/0x12C row_ror:1/2/4/8/12
template <int CTRL>
__device__ __forceinline__ float dppx(float x) {
    int xi = __float_as_int(x);
    return __int_as_float(__builtin_amdgcn_update_dpp(xi, xi, CTRL, 0xF, 0xF, false));
}

// y[lane] = v[lane^4] via row_ror (VALU) — R15/R16 hardware-proven
__device__ __forceinline__ float xor4v(float v, bool m4) {
    float a = dppx<0x124>(v);
    float c = dppx<0x12C>(v);
    return m4 ? c : a;
}

// y[lane] = v[lane^16] via permlane16_swap builtin (VALU) — R15/R16 proven
__device__ __forceinline__ float xchg16(float v, bool m16) {
    u32x2 r = __builtin_amdgcn_permlane16_swap(
        __float_as_uint(v), __float_as_uint(v), false, false);
    return m16 ? __uint_as_float(r.x) : __uint_as_float(r.y);
}

// y[lane] = v[lane^32] via permlane32_swap builtin (VALU) — R15/R16 proven
__device__ __forceinline__ float xchg32(float v, bool m32) {
    u32x2 r = __builtin_amdgcn_permlane32_swap(
        __float_as_uint(v), __float_as_uint(v), false, false);
    return m32 ? __uint_as_float(r.x) : __uint_as_float(r.y);
}

// packed f32 FMA; op_sel variants broadcast the lo/hi half of the 64-bit
// h-pair to both product halves (R12-proven, 687µs kernel)
__device__ __forceinline__ void pkfma_lo(v2f& acc, v2f w, v2f h) {
    asm("v_pk_fma_f32 %0, %1, %2, %0 op_sel_hi:[1,0,1]"
        : "+v"(acc) : "v"(w), "v"(h));
}
__device__ __forceinline__ void pkfma_hi(v2f& acc, v2f w, v2f h) {
    asm("v_pk_fma_f32 %0, %1, %2, %0 op_sel:[0,1,0] op_sel_hi:[1,1,1]"
        : "+v"(acc) : "v"(w), "v"(h));
}

// full 64-lane sum via DPP rotates + row broadcasts; uniform result (lane 63)
__device__ __forceinline__ float wave_sum(float v) {
    v += dppx<0x121>(v);                       // ror:1
    v += dppx<0x122>(v);                       // ror:2
    v += dppx<0x124>(v);                       // ror:4
    v += dppx<0x128>(v);                       // ror:8  -> 16-row totals
    v += __int_as_float(__builtin_amdgcn_update_dpp(
            0, __float_as_int(v), 0x142, 0xA, 0xF, false));   // bcast15
    v += __int_as_float(__builtin_amdgcn_update_dpp(
            0, __float_as_int(v), 0x143, 0xC, 0xF, false));   // bcast31
    return __int_as_float(__builtin_amdgcn_readlane(__float_as_int(v), 63));
}

__device__ __forceinline__ constexpr int rev3(int x) {   // 3-bit reversal
    return ((x & 1) << 2) | (x & 2) | ((x >> 2) & 1);
}

__global__ __launch_bounds__(256) __attribute__((amdgpu_waves_per_eu(2, 2)))
void hnn_rk4_kernel(
        const float* __restrict__ tarr,
        const float* __restrict__ x0,
        const float* __restrict__ W1,
        const float* __restrict__ b1,
        const float* __restrict__ W2,
        const float* __restrict__ b2,
        const float* __restrict__ W3,
        float* __restrict__ out)
{
    const int lane = threadIdx.x & 63;
    const int wid  = threadIdx.x >> 6;
    const int b    = blockIdx.x * 4 + wid;     // one wave per batch element

    // per-wave 64-float broadcast buffer, indexed by UNIT number
    __shared__ alignas(16) float sbuf[4][64];
    float* sb = sbuf[wid];

    // 8x8 lane grid (R8/R12 proven): lane (rr,cc) owns W2 rows 8rr..+7 x cols
    // 8cc..+7, hidden unit uo = 8rr+rev3(cc); ends holding u[vu], vu=8cc+rev3(rr).
    const int rr = lane >> 3, cc = lane & 7;
    const int pc = rev3(cc),  pr = rev3(rr);
    const int uo = 8 * rr + pc;
    const int vu = 8 * cc + pr;

    const float dt  = tarr[1] - tarr[0];
    const float hdt = 0.5f * dt;
    const float sdt = dt * (1.0f / 6.0f);

    const float w1a = W1[2 * uo + 0];
    const float w1b = W1[2 * uo + 1];
    const float b1i = b1[uo];
    const float b2i = b2[uo];
    const float w3i = W3[uo];
    const float w1vb  = W1[2 * vu + 1];
    const float nw1va = -W1[2 * vu + 0];       // folded negate for kp

    // weight pairs (R12 layout, proven):
    //   wsF[t][m] = ( W2[8rr+((2m)^pc)][8cc+t], W2[8rr+((2m+1)^pc)][8cc+t] )
    //   wsB[o][m] = ( W2[8rr+o][8cc+((2m)^pr)], W2[8rr+o][8cc+((2m+1)^pr)] )
    v2f wsF[8][4], wsB[8][4];
#pragma unroll
    for (int t = 0; t < 8; ++t) {
#pragma unroll
        for (int m = 0; m < 4; ++m) {
            v2f f;
            f.x = W2[(8 * rr + ((2 * m)     ^ pc)) * HID + 8 * cc + t];
            f.y = W2[(8 * rr + ((2 * m + 1) ^ pc)) * HID + 8 * cc + t];
            wsF[t][m] = f;
            v2f g;
            g.x = W2[(8 * rr + t) * HID + 8 * cc + ((2 * m)     ^ pr)];
            g.y = W2[(8 * rr + t) * HID + 8 * cc + ((2 * m + 1) ^ pr)];
            wsB[t][m] = g;
        }
    }
    // setup-only pins (R12-proven; in-loop "+a" re-pins = R14 scratch disaster)
#pragma unroll
    for (int t = 0; t < 8; ++t)
#pragma unroll
        for (int m = 0; m < 4; ++m)
            asm("" : "+v"(wsF[t][m]), "+v"(wsB[t][m]));

    const bool m4 = lane & 4, m16 = lane & 16, m32 = lane & 32;

    float q = x0[2 * b + 0];
    float p = x0[2 * b + 1];

    if (lane == 0) {
        out[2 * b + 0] = q;
        out[2 * b + 1] = p;
    }

    auto dynamics = [&](float xq, float xp, float& kq, float& kp) {
        // layer 1 (own unit)
        const float h1 = fast_tanh(fmaf(w1a, xq, fmaf(w1b, xp, b1i)));

        // ---- broadcast h1 via LDS: scatter-write by unit, contiguous b128
        // reads (same-wave DS in-order; no barrier — R2/R12 proven)
        sb[uo] = h1;
        const v4f r0 = *(const v4f*)(sb + 8 * cc);      // h1[8cc+0..3]
        const v4f r1 = *(const v4f*)(sb + 8 * cc + 4);  // h1[8cc+4..7]
        const float h1v = sb[vu];                       // h1 of held unit vu
        const v2f h01 = r0.xy, h23 = r0.zw, h45 = r1.xy, h67 = r1.zw;

        // ---- forward: pre2 = W2 h1 + b2 (packed, op_sel broadcast) ----
        v2f P0 = {0.f,0.f}, P1 = {0.f,0.f}, P2 = {0.f,0.f}, P3 = {0.f,0.f};
        pkfma_lo(P0, wsF[0][0], h01); pkfma_lo(P1, wsF[0][1], h01);
        pkfma_lo(P2, wsF[0][2], h01); pkfma_lo(P3, wsF[0][3], h01);
        pkfma_hi(P0, wsF[1][0], h01); pkfma_hi(P1, wsF[1][1], h01);
        pkfma_hi(P2, wsF[1][2], h01); pkfma_hi(P3, wsF[1][3], h01);
        pkfma_lo(P0, wsF[2][0], h23); pkfma_lo(P1, wsF[2][1], h23);
        pkfma_lo(P2, wsF[2][2], h23); pkfma_lo(P3, wsF[2][3], h23);
        pkfma_hi(P0, wsF[3][0], h23); pkfma_hi(P1, wsF[3][1], h23);
        pkfma_hi(P2, wsF[3][2], h23); pkfma_hi(P3, wsF[3][3], h23);
        pkfma_lo(P0, wsF[4][0], h45); pkfma_lo(P1, wsF[4][1], h45);
        pkfma_lo(P2, wsF[4][2], h45); pkfma_lo(P3, wsF[4][3], h45);
        pkfma_hi(P0, wsF[5][0], h45); pkfma_hi(P1, wsF[5][1], h45);
        pkfma_hi(P2, wsF[5][2], h45); pkfma_hi(P3, wsF[5][3], h45);
        pkfma_lo(P0, wsF[6][0], h67); pkfma_lo(P1, wsF[6][1], h67);
        pkfma_lo(P2, wsF[6][2], h67); pkfma_lo(P3, wsF[6][3], h67);
        pkfma_hi(P0, wsF[7][0], h67); pkfma_hi(P1, wsF[7][1], h67);
        pkfma_hi(P2, wsF[7][2], h67); pkfma_hi(P3, wsF[7][3], h67);

        // uniform scatter-reduce over cc bits — all VALU now
        P0.x += dppx<0xB1>(P2.x);  P0.y += dppx<0xB1>(P2.y);
        P1.x += dppx<0xB1>(P3.x);  P1.y += dppx<0xB1>(P3.y);
        P0.x += dppx<0x4E>(P1.x);  P0.y += dppx<0x4E>(P1.y);
        const float pre2 = P0.x + xor4v(P0.y, m4) + b2i;

        const float h2 = fast_tanh(pre2);
        const float g2 = w3i * fmaf(-h2, h2, 1.0f);

        // ---- broadcast g2 via LDS (h1 reads already retired: in-order pipe)
        sb[uo] = g2;
        const v4f s0 = *(const v4f*)(sb + 8 * rr);      // g2[8rr+0..3]
        const v4f s1 = *(const v4f*)(sb + 8 * rr + 4);  // g2[8rr+4..7]
        const v2f g01 = s0.xy, g23 = s0.zw, g45 = s1.xy, g67 = s1.zw;

        // ---- backward: u = W2^T g2 (packed, op_sel broadcast) ----
        v2f Q0 = {0.f,0.f}, Q1 = {0.f,0.f}, Q2 = {0.f,0.f}, Q3 = {0.f,0.f};
        pkfma_lo(Q0, wsB[0][0], g01); pkfma_lo(Q1, wsB[0][1], g01);
        pkfma_lo(Q2, wsB[0][2], g01); pkfma_lo(Q3, wsB[0][3], g01);
        pkfma_hi(Q0, wsB[1][0], g01); pkfma_hi(Q1, wsB[1][1], g01);
        pkfma_hi(Q2, wsB[1][2], g01); pkfma_hi(Q3, wsB[1][3], g01);
        pkfma_lo(Q0, wsB[2][0], g23); pkfma_lo(Q1, wsB[2][1], g23);
        pkfma_lo(Q2, wsB[2][2], g23); pkfma_lo(Q3, wsB[2][3], g23);
        pkfma_hi(Q0, wsB[3][0], g23); pkfma_hi(Q1, wsB[3][1], g23);
        pkfma_hi(Q2, wsB[3][2], g23); pkfma_hi(Q3, wsB[3][3], g23);
        pkfma_lo(Q0, wsB[4][0], g45); pkfma_lo(Q1, wsB[4][1], g45);
        pkfma_lo(Q2, wsB[4][2], g45); pkfma_lo(Q3, wsB[4][3], g45);
        pkfma_hi(Q0, wsB[5][0], g45); pkfma_hi(Q1, wsB[5][1], g45);
        pkfma_hi(Q2, wsB[5][2], g45); pkfma_hi(Q3, wsB[5][3], g45);
        pkfma_lo(Q0, wsB[6][0], g67); pkfma_lo(Q1, wsB[6][1], g67);
        pkfma_lo(Q2, wsB[6][2], g67); pkfma_lo(Q3, wsB[6][3], g67);
        pkfma_hi(Q0, wsB[7][0], g67); pkfma_hi(Q1, wsB[7][1], g67);
        pkfma_hi(Q2, wsB[7][2], g67); pkfma_hi(Q3, wsB[7][3], g67);

        // scatter-reduce over rr bits — all VALU (xor8 DPP, xor16/32 permlane)
        Q0.x += dppx<0x128>(Q2.x);  Q0.y += dppx<0x128>(Q2.y);
        Q1.x += dppx<0x128>(Q3.x);  Q1.y += dppx<0x128>(Q3.y);
        Q0.x += xchg16(Q1.x, m16);  Q0.y += xchg16(Q1.y, m16);
        const float uv = Q0.x + xchg32(Q0.y, m32);     // = u[vu], stays here

        // dH/dx contribution of unit vu; wave_sum is landing-agnostic
        const float g1v = uv * fmaf(-h1v, h1v, 1.0f);

        kq = wave_sum(g1v * w1vb);    //  dH/dp
        kp = wave_sum(g1v * nw1va);   // -dH/dq (negate pre-folded)
    };

#pragma unroll 1
    for (int s = 0; s < TSTEPS - 1; ++s) {
        float kq1, kp1, kq2, kp2, kq3, kp3, kq4, kp4;
        dynamics(q, p, kq1, kp1);
        dynamics(fmaf(hdt, kq1, q), fmaf(hdt, kp1, p), kq2, kp2);
        dynamics(fmaf(hdt, kq2, q), fmaf(hdt, kp2, p), kq3, kp3);
        dynamics(fmaf(dt,  kq3, q), fmaf(dt,  kp3, p), kq4, kp4);
        q = fmaf(sdt, (kq1 + kq4) + 2.0f * (kq2 + kq3), q);
        p = fmaf(sdt, (kp1 + kp4) + 2.0f * (kp2 + kp3), p);
        if (lane == 0) {
            out[(s + 1) * (BATCH * 2) + 2 * b + 0] = q;
            out[(s + 1) * (BATCH * 2) + 2 * b + 1] = p;
        }
    }
}

extern "C" void kernel_launch(void* const* d_in, const int* in_sizes, int n_in,
                              void* d_out, int out_size, void* d_ws, size_t ws_size,
                              hipStream_t stream) {
    const float* t  = (const float*)d_in[0];
    const float* x0 = (const float*)d_in[1];
    const float* W1 = (const float*)d_in[2];
    const float* b1 = (const float*)d_in[3];
    const float* W2 = (const float*)d_in[4];
    const float* b2 = (const float*)d_in[5];
    const float* W3 = (const float*)d_in[6];
    // d_in[7] = b3: additive constant in H, cancels in dH/dx — unused.

    hnn_rk4_kernel<<<dim3(BATCH / 4), dim3(256), 0, stream>>>(
        t, x0, W1, b1, W2, b2, W3, (float*)d_out);
}

// Round 18
// 683.835 us; speedup vs baseline: 4.6294x; 1.0669x over previous
//
#include <hip/hip_runtime.h>

#define HID    64
#define TSTEPS 256
#define BATCH  2048

typedef float v2f __attribute__((ext_vector_type(2)));
typedef float v4f __attribute__((ext_vector_type(4)));

// tanh(x) = 1 - 2/(exp2(2*log2(e)*x) + 1); exact at saturation
__device__ __forceinline__ float fast_tanh(float x) {
    float e = __builtin_amdgcn_exp2f(x * 2.8853900817779268f);
    float r = __builtin_amdgcn_rcpf(e + 1.0f);
    return fmaf(-2.0f, r, 1.0f);
}

// ds_swizzle xor-exchange within 32-lane halves (BitMode: xor=M, and=0x1F)
template <int M>
__device__ __forceinline__ float swz(float v) {
    return __int_as_float(__builtin_amdgcn_ds_swizzle(
        __float_as_int(v), (M << 10) | 0x1F));
}

// DPP move: 0xB1 quad_perm lane^1, 0x4E quad_perm lane^2,
// 0x121/0x122/0x124/0x128 row_ror:1/2/4/8
template <int CTRL>
__device__ __forceinline__ float dppx(float x) {
    int xi = __float_as_int(x);
    return __int_as_float(__builtin_amdgcn_update_dpp(xi, xi, CTRL, 0xF, 0xF, false));
}

__device__ __forceinline__ float bperm(int addr, float v) {
    return __int_as_float(__builtin_amdgcn_ds_bpermute(addr, __float_as_int(v)));
}

// packed f32 FMA; op_sel variants broadcast the lo/hi half of the 64-bit
// h-pair to both product halves (R12-proven, 687µs kernel)
__device__ __forceinline__ void pkfma_lo(v2f& acc, v2f w, v2f h) {
    asm("v_pk_fma_f32 %0, %1, %2, %0 op_sel_hi:[1,0,1]"
        : "+v"(acc) : "v"(w), "v"(h));
}
__device__ __forceinline__ void pkfma_hi(v2f& acc, v2f w, v2f h) {
    asm("v_pk_fma_f32 %0, %1, %2, %0 op_sel:[0,1,0] op_sel_hi:[1,1,1]"
        : "+v"(acc) : "v"(w), "v"(h));
}

// dual 64-lane all-reduce: 4 DPP ror stages (16-row all-reduce, VALU) then
// xor16 (ds_swizzle) + xor32 (bperm) butterflies on the DS pipe, both
// components interleaved so the two DS trips overlap. Result uniform on ALL
// lanes — no readlane / row_bcast needed.
__device__ __forceinline__ void allred2(float& a, float& b, int a32) {
    a += dppx<0x121>(a);  b += dppx<0x121>(b);   // ror:1
    a += dppx<0x122>(a);  b += dppx<0x122>(b);   // ror:2
    a += dppx<0x124>(a);  b += dppx<0x124>(b);   // ror:4
    a += dppx<0x128>(a);  b += dppx<0x128>(b);   // ror:8 -> 16-row totals
    float ta = swz<16>(a), tb = swz<16>(b);      // xor16, both in flight
    a += ta;  b += tb;
    float ua = bperm(a32, a), ub = bperm(a32, b);// xor32, both in flight
    a += ua;  b += ub;
}

__device__ __forceinline__ constexpr int rev3(int x) {   // 3-bit reversal
    return ((x & 1) << 2) | (x & 2) | ((x >> 2) & 1);
}

__global__ __launch_bounds__(256) __attribute__((amdgpu_waves_per_eu(2, 2)))
void hnn_rk4_kernel(
        const float* __restrict__ tarr,
        const float* __restrict__ x0,
        const float* __restrict__ W1,
        const float* __restrict__ b1,
        const float* __restrict__ W2,
        const float* __restrict__ b2,
        const float* __restrict__ W3,
        float* __restrict__ out)
{
    const int lane = threadIdx.x & 63;
    const int wid  = threadIdx.x >> 6;
    const int b    = blockIdx.x * 4 + wid;     // one wave per batch element

    // per-wave 64-float broadcast buffer, indexed by UNIT number
    __shared__ alignas(16) float sbuf[4][64];
    float* sb = sbuf[wid];

    // 8x8 lane grid (R8/R12 proven): lane (rr,cc) owns W2 rows 8rr..+7 x cols
    // 8cc..+7, hidden unit uo = 8rr+rev3(cc); ends holding u[vu], vu=8cc+rev3(rr).
    const int rr = lane >> 3, cc = lane & 7;
    const int pc = rev3(cc),  pr = rev3(rr);
    const int uo = 8 * rr + pc;
    const int vu = 8 * cc + pr;

    const float dt  = tarr[1] - tarr[0];
    const float hdt = 0.5f * dt;
    const float sdt = dt * (1.0f / 6.0f);

    const float w1a = W1[2 * uo + 0];
    const float w1b = W1[2 * uo + 1];
    const float b1i = b1[uo];
    const float b2i = b2[uo];
    const float w3i = W3[uo];
    const float w1vb  = W1[2 * vu + 1];
    const float nw1va = -W1[2 * vu + 0];       // folded negate for kp

    int a32 = (lane ^ 32) * 4;                 // xor32 exchange address

    // weight pairs (R12 layout, proven):
    //   wsF[t][m] = ( W2[8rr+((2m)^pc)][8cc+t], W2[8rr+((2m+1)^pc)][8cc+t] )
    //   wsB[o][m] = ( W2[8rr+o][8cc+((2m)^pr)], W2[8rr+o][8cc+((2m+1)^pr)] )
    v2f wsF[8][4], wsB[8][4];
#pragma unroll
    for (int t = 0; t < 8; ++t) {
#pragma unroll
        for (int m = 0; m < 4; ++m) {
            v2f f;
            f.x = W2[(8 * rr + ((2 * m)     ^ pc)) * HID + 8 * cc + t];
            f.y = W2[(8 * rr + ((2 * m + 1) ^ pc)) * HID + 8 * cc + t];
            wsF[t][m] = f;
            v2f g;
            g.x = W2[(8 * rr + t) * HID + 8 * cc + ((2 * m)     ^ pr)];
            g.y = W2[(8 * rr + t) * HID + 8 * cc + ((2 * m + 1) ^ pr)];
            wsB[t][m] = g;
        }
    }
    // setup-only pins (R12-proven; in-loop "+a" re-pins = R14 scratch disaster)
#pragma unroll
    for (int t = 0; t < 8; ++t)
#pragma unroll
        for (int m = 0; m < 4; ++m)
            asm("" : "+v"(wsF[t][m]), "+v"(wsB[t][m]));

    float q = x0[2 * b + 0];
    float p = x0[2 * b + 1];

    if (lane == 0) {
        out[2 * b + 0] = q;
        out[2 * b + 1] = p;
    }

    auto dynamics = [&](float xq, float xp, float& kq, float& kp) {
        // layer 1 (own unit)
        const float h1 = fast_tanh(fmaf(w1a, xq, fmaf(w1b, xp, b1i)));

        // ---- broadcast h1 via LDS: scatter-write by unit, contiguous b128
        // reads (same-wave DS in-order; no barrier — R2/R12 proven)
        sb[uo] = h1;
        const v4f r0 = *(const v4f*)(sb + 8 * cc);      // h1[8cc+0..3]
        const v4f r1 = *(const v4f*)(sb + 8 * cc + 4);  // h1[8cc+4..7]
        const float h1v = sb[vu];                       // h1 of held unit vu
        const v2f h01 = r0.xy, h23 = r0.zw, h45 = r1.xy, h67 = r1.zw;

        // ---- forward: pre2 = W2 h1 + b2 (packed, op_sel broadcast) ----
        v2f P0 = {0.f,0.f}, P1 = {0.f,0.f}, P2 = {0.f,0.f}, P3 = {0.f,0.f};
        pkfma_lo(P0, wsF[0][0], h01); pkfma_lo(P1, wsF[0][1], h01);
        pkfma_lo(P2, wsF[0][2], h01); pkfma_lo(P3, wsF[0][3], h01);
        pkfma_hi(P0, wsF[1][0], h01); pkfma_hi(P1, wsF[1][1], h01);
        pkfma_hi(P2, wsF[1][2], h01); pkfma_hi(P3, wsF[1][3], h01);
        pkfma_lo(P0, wsF[2][0], h23); pkfma_lo(P1, wsF[2][1], h23);
        pkfma_lo(P2, wsF[2][2], h23); pkfma_lo(P3, wsF[2][3], h23);
        pkfma_hi(P0, wsF[3][0], h23); pkfma_hi(P1, wsF[3][1], h23);
        pkfma_hi(P2, wsF[3][2], h23); pkfma_hi(P3, wsF[3][3], h23);
        pkfma_lo(P0, wsF[4][0], h45); pkfma_lo(P1, wsF[4][1], h45);
        pkfma_lo(P2, wsF[4][2], h45); pkfma_lo(P3, wsF[4][3], h45);
        pkfma_hi(P0, wsF[5][0], h45); pkfma_hi(P1, wsF[5][1], h45);
        pkfma_hi(P2, wsF[5][2], h45); pkfma_hi(P3, wsF[5][3], h45);
        pkfma_lo(P0, wsF[6][0], h67); pkfma_lo(P1, wsF[6][1], h67);
        pkfma_lo(P2, wsF[6][2], h67); pkfma_lo(P3, wsF[6][3], h67);
        pkfma_hi(P0, wsF[7][0], h67); pkfma_hi(P1, wsF[7][1], h67);
        pkfma_hi(P2, wsF[7][2], h67); pkfma_hi(P3, wsF[7][3], h67);

        // uniform scatter-reduce over cc bits (R12-verbatim: DS swz4 tail)
        P0.x += dppx<0xB1>(P2.x);  P0.y += dppx<0xB1>(P2.y);
        P1.x += dppx<0xB1>(P3.x);  P1.y += dppx<0xB1>(P3.y);
        P0.x += dppx<0x4E>(P1.x);  P0.y += dppx<0x4E>(P1.y);
        const float pre2 = P0.x + swz<4>(P0.y) + b2i;

        const float h2 = fast_tanh(pre2);
        const float g2 = w3i * fmaf(-h2, h2, 1.0f);

        // ---- broadcast g2 via LDS (h1 reads already retired: in-order pipe)
        sb[uo] = g2;
        const v4f s0 = *(const v4f*)(sb + 8 * rr);      // g2[8rr+0..3]
        const v4f s1 = *(const v4f*)(sb + 8 * rr + 4);  // g2[8rr+4..7]
        const v2f g01 = s0.xy, g23 = s0.zw, g45 = s1.xy, g67 = s1.zw;

        // ---- backward: u = W2^T g2 (packed, op_sel broadcast) ----
        v2f Q0 = {0.f,0.f}, Q1 = {0.f,0.f}, Q2 = {0.f,0.f}, Q3 = {0.f,0.f};
        pkfma_lo(Q0, wsB[0][0], g01); pkfma_lo(Q1, wsB[0][1], g01);
        pkfma_lo(Q2, wsB[0][2], g01); pkfma_lo(Q3, wsB[0][3], g01);
        pkfma_hi(Q0, wsB[1][0], g01); pkfma_hi(Q1, wsB[1][1], g01);
        pkfma_hi(Q2, wsB[1][2], g01); pkfma_hi(Q3, wsB[1][3], g01);
        pkfma_lo(Q0, wsB[2][0], g23); pkfma_lo(Q1, wsB[2][1], g23);
        pkfma_lo(Q2, wsB[2][2], g23); pkfma_lo(Q3, wsB[2][3], g23);
        pkfma_hi(Q0, wsB[3][0], g23); pkfma_hi(Q1, wsB[3][1], g23);
        pkfma_hi(Q2, wsB[3][2], g23); pkfma_hi(Q3, wsB[3][3], g23);
        pkfma_lo(Q0, wsB[4][0], g45); pkfma_lo(Q1, wsB[4][1], g45);
        pkfma_lo(Q2, wsB[4][2], g45); pkfma_lo(Q3, wsB[4][3], g45);
        pkfma_hi(Q0, wsB[5][0], g45); pkfma_hi(Q1, wsB[5][1], g45);
        pkfma_hi(Q2, wsB[5][2], g45); pkfma_hi(Q3, wsB[5][3], g45);
        pkfma_lo(Q0, wsB[6][0], g67); pkfma_lo(Q1, wsB[6][1], g67);
        pkfma_lo(Q2, wsB[6][2], g67); pkfma_lo(Q3, wsB[6][3], g67);
        pkfma_hi(Q0, wsB[7][0], g67); pkfma_hi(Q1, wsB[7][1], g67);
        pkfma_hi(Q2, wsB[7][2], g67); pkfma_hi(Q3, wsB[7][3], g67);

        // scatter-reduce over rr bits (R12-verbatim: DS swz16/bperm tail)
        Q0.x += dppx<0x128>(Q2.x);  Q0.y += dppx<0x128>(Q2.y);
        Q1.x += dppx<0x128>(Q3.x);  Q1.y += dppx<0x128>(Q3.y);
        Q0.x += swz<16>(Q1.x);      Q0.y += swz<16>(Q1.y);
        const float uv = Q0.x + bperm(a32, Q0.y);     // = u[vu], stays here

        // dH/dx contribution of unit vu; dual butterfly all-reduce (uniform)
        const float g1v = uv * fmaf(-h1v, h1v, 1.0f);
        float sq = g1v * w1vb;      //  dH/dp partial
        float sp = g1v * nw1va;     // -dH/dq partial
        allred2(sq, sp, a32);
        kq = sq;
        kp = sp;
    };

#pragma unroll 1
    for (int s = 0; s < TSTEPS - 1; ++s) {
        float kq1, kp1, kq2, kp2, kq3, kp3, kq4, kp4;
        dynamics(q, p, kq1, kp1);
        dynamics(fmaf(hdt, kq1, q), fmaf(hdt, kp1, p), kq2, kp2);
        dynamics(fmaf(hdt, kq2, q), fmaf(hdt, kp2, p), kq3, kp3);
        dynamics(fmaf(dt,  kq3, q), fmaf(dt,  kp3, p), kq4, kp4);
        q = fmaf(sdt, (kq1 + kq4) + 2.0f * (kq2 + kq3), q);
        p = fmaf(sdt, (kp1 + kp4) + 2.0f * (kp2 + kp3), p);
        if (lane == 0) {
            out[(s + 1) * (BATCH * 2) + 2 * b + 0] = q;
            out[(s + 1) * (BATCH * 2) + 2 * b + 1] = p;
        }
    }
}

extern "C" void kernel_launch(void* const* d_in, const int* in_sizes, int n_in,
                              void* d_out, int out_size, void* d_ws, size_t ws_size,
                              hipStream_t stream) {
    const float* t  = (const float*)d_in[0];
    const float* x0 = (const float*)d_in[1];
    const float* W1 = (const float*)d_in[2];
    const float* b1 = (const float*)d_in[3];
    const float* W2 = (const float*)d_in[4];
    const float* b2 = (const float*)d_in[5];
    const float* W3 = (const float*)d_in[6];
    // d_in[7] = b3: additive constant in H, cancels in dH/dx — unused.

    hnn_rk4_kernel<<<dim3(BATCH / 4), dim3(256), 0, stream>>>(
        t, x0, W1, b1, W2, b2, W3, (float*)d_out);
}